// Round 1
// baseline (300.587 us; speedup 1.0000x reference)
//
#include <hip/hip_runtime.h>
#include <hip/hip_fp16.h>
#include <cstdint>

#define B_   4
#define S_   2048
#define HID_ 1024
#define NH_  16
#define HD_  64
#define M_   (B_ * S_)   // 8192

using f16   = _Float16;
using f16x4 = __attribute__((ext_vector_type(4))) _Float16;
using f16x8 = __attribute__((ext_vector_type(8))) _Float16;
using f32x4 = __attribute__((ext_vector_type(4))) float;

// async 16B global -> LDS (HW writes wave-uniform base + lane*16)
__device__ __forceinline__ void g2lds16(const void* g, void* l) {
  __builtin_amdgcn_global_load_lds(
      (__attribute__((address_space(1))) void*)(uintptr_t)g,
      (__attribute__((address_space(3))) void*)(uint32_t)(uintptr_t)l,
      16, 0, 0);
}

// ---------------- f32 -> f16 convert ----------------
__global__ void cvt_f32_f16_k(const float* __restrict__ src, f16* __restrict__ dst, int n4) {
  int i = blockIdx.x * blockDim.x + threadIdx.x;
  if (i >= n4) return;
  float4 v = ((const float4*)src)[i];
  f16x4 h;
  h[0] = (f16)v.x; h[1] = (f16)v.y; h[2] = (f16)v.z; h[3] = (f16)v.w;
  ((f16x4*)dst)[i] = h;
}

// ---------------- fused QKV projection GEMM ----------------
// C[row, col] = sum_k A[row,k] * W[col,k] + bias[col], M=8192, N=3072, K=1024
// 128x128 tile, BK=64, 4 waves each 64x64, 16x16x32 f16 MFMA.
// LDS layout: per row 8 chunks of 16B, chunk XOR-swizzled by (row&7); staged
// linearly via global_load_lds with pre-swizzled SOURCE addresses.
__global__ __launch_bounds__(256) void proj_gemm_k(
    const f16* __restrict__ A, const f16* __restrict__ W,
    const float* __restrict__ bq, const float* __restrict__ bk, const float* __restrict__ bv,
    f16* __restrict__ Out) {
  __shared__ __align__(16) f16 As[128 * 64];
  __shared__ __align__(16) f16 Bs[128 * 64];
  const int tid = threadIdx.x;
  const int l   = tid & 63;
  const int w   = tid >> 6;
  const int lr  = l & 15;
  const int lk  = (l >> 4) * 8;
  const int col0 = blockIdx.x * 128;  // 0..23 -> N
  const int row0 = blockIdx.y * 128;  // 0..63 -> M
  const int wr = (w >> 1) * 64;
  const int wc = (w & 1) * 64;

  f32x4 acc[4][4] = {};

  for (int kt = 0; kt < 16; ++kt) {
    const int k0 = kt * 64;
#pragma unroll
    for (int i = 0; i < 4; ++i) {
      const int c   = tid + i * 256;    // chunk 0..1023
      const int row = c >> 3;
      const int cb  = (c ^ row) & 7;    // logical chunk (inverse swizzle)
      g2lds16(A + (size_t)(row0 + row) * 1024 + k0 + cb * 8,
              As + (w * 64 + i * 256) * 8);
      g2lds16(W + (size_t)(col0 + row) * 1024 + k0 + cb * 8,
              Bs + (w * 64 + i * 256) * 8);
    }
    asm volatile("s_waitcnt vmcnt(0)" ::: "memory");
    __syncthreads();

#pragma unroll
    for (int kk = 0; kk < 64; kk += 32) {
      const int x = (kk + lk) >> 3;
      f16x8 af[4], bf[4];
#pragma unroll
      for (int m = 0; m < 4; ++m) {
        const int row = wr + m * 16 + lr;
        af[m] = *(const f16x8*)(As + (row * 8 + ((x ^ row) & 7)) * 8);
      }
#pragma unroll
      for (int n = 0; n < 4; ++n) {
        const int row = wc + n * 16 + lr;
        bf[n] = *(const f16x8*)(Bs + (row * 8 + ((x ^ row) & 7)) * 8);
      }
#pragma unroll
      for (int m = 0; m < 4; ++m)
#pragma unroll
        for (int n = 0; n < 4; ++n)
          acc[m][n] = __builtin_amdgcn_mfma_f32_16x16x32_f16(af[m], bf[n], acc[m][n], 0, 0, 0);
    }
    __syncthreads();
  }

  const int proj = col0 >> 10;  // block never straddles a projection (1024%128==0)
  const float* bias = (proj == 0) ? bq : ((proj == 1) ? bk : bv);
  f16* outp = Out + (size_t)proj * ((size_t)M_ * HID_);
#pragma unroll
  for (int n = 0; n < 4; ++n) {
    const int col = col0 + wc + n * 16 + lr;
    const int cp  = col & 1023;
    const float bb = bias[cp];
#pragma unroll
    for (int m = 0; m < 4; ++m) {
      const int rbase = row0 + wr + m * 16 + (l >> 4) * 4;
#pragma unroll
      for (int r = 0; r < 4; ++r)
        outp[(size_t)(rbase + r) * 1024 + cp] = (f16)(acc[m][n][r] + bb);
    }
  }
}

// ---------------- keff + V-transpose prep ----------------
// keff[bh][s][d] = k/8 + softsign(softsign(k)/8) + v   (f16)
// vt[bh][d][s]   = v transposed (f16), so attention can stage it linearly.
__global__ __launch_bounds__(256) void prep_kv_k(
    const f16* __restrict__ Kp, const f16* __restrict__ Vp,
    f16* __restrict__ Keff, f16* __restrict__ Vt) {
  const int bh = blockIdx.x;  // 64
  const int st = blockIdx.y;  // 32
  const int b = bh >> 4, h = bh & 15;
  const int tid = threadIdx.x;
#pragma unroll
  for (int i = 0; i < 2; ++i) {
    const int c  = tid + i * 256;     // 0..511
    const int sl = c >> 3, cb = c & 7;
    const int s  = st * 64 + sl;
    const size_t src = (size_t)(b * S_ + s) * 1024 + h * 64 + cb * 8;
    const f16x8 kv = *(const f16x8*)(Kp + src);
    const f16x8 vv = *(const f16x8*)(Vp + src);
    f16x8 ke;
#pragma unroll
    for (int j = 0; j < 8; ++j) {
      const float kf = (float)kv[j], vf = (float)vv[j];
      const float s1 = kf / (1.f + fabsf(kf));
      const float t  = s1 * 0.125f;
      const float s2 = t / (1.f + fabsf(t));
      ke[j] = (f16)(kf * 0.125f + s2 + vf);
    }
    *(f16x8*)(Keff + ((size_t)bh * S_ + s) * 64 + cb * 8) = ke;
#pragma unroll
    for (int j = 0; j < 8; ++j)
      Vt[((size_t)bh * 64 + cb * 8 + j) * S_ + s] = vv[j];
  }
}

// ---------------- flash attention ----------------
// block = (bh, qtile of 64 rows), 4 waves x 16 q-rows each; K/V tiles of 64.
__global__ __launch_bounds__(256) void attn_k(
    const f16* __restrict__ Q,     // [8192][1024]
    const f16* __restrict__ Keff,  // [64][2048][64]
    const f16* __restrict__ Vt,    // [64][64][2048]
    const int* __restrict__ mask,  // [4][2048]
    float* __restrict__ Out) {     // [8192][1024] f32
  __shared__ __align__(16) f16 Kl[64 * 64];
  __shared__ __align__(16) f16 Vl[64 * 64];
  __shared__ __align__(16) f16 Pl[4][16][88];   // pad 88 -> 2-way-free b128 reads
  const int bh = blockIdx.x, qt = blockIdx.y;
  const int b = bh >> 4, h = bh & 15;
  const int tid = threadIdx.x;
  const int l = tid & 63, w = tid >> 6;
  const int lr = l & 15, lk = (l >> 4) * 8;

  // Q fragments held in registers for the whole kernel
  f16x8 qf0, qf1;
  {
    const int qrow = qt * 64 + w * 16 + lr;
    const f16* qs = Q + (size_t)(b * S_ + qrow) * 1024 + h * 64 + lk;
    qf0 = *(const f16x8*)(qs);
    qf1 = *(const f16x8*)(qs + 32);
  }
  int mrow[4];
#pragma unroll
  for (int r = 0; r < 4; ++r)
    mrow[r] = mask[b * S_ + qt * 64 + w * 16 + (l >> 4) * 4 + r];

  float m_run[4], l_run[4];
#pragma unroll
  for (int r = 0; r < 4; ++r) { m_run[r] = -1e30f; l_run[r] = 0.f; }
  f32x4 ctx[4] = {};

  for (int kt = 0; kt < 32; ++kt) {
    // stage K tile [64 k][64 d] and Vt tile [64 d][64 k] (swizzled source)
#pragma unroll
    for (int i = 0; i < 2; ++i) {
      const int c   = tid + i * 256;
      const int row = c >> 3;
      const int cb  = (c ^ row) & 7;
      g2lds16(Keff + ((size_t)bh * S_ + (size_t)kt * 64 + row) * 64 + cb * 8,
              Kl + (w * 64 + i * 256) * 8);
      g2lds16(Vt + ((size_t)bh * 64 + row) * S_ + (size_t)kt * 64 + cb * 8,
              Vl + (w * 64 + i * 256) * 8);
    }
    asm volatile("s_waitcnt vmcnt(0)" ::: "memory");
    __syncthreads();

    // S = Q * Keff^T / 8  (per wave: 16 q x 64 k)
    float sv[4][4];
#pragma unroll
    for (int cb = 0; cb < 4; ++cb) {
      f32x4 a = {};
#pragma unroll
      for (int kk = 0; kk < 2; ++kk) {
        const int row = cb * 16 + lr;
        const int x   = (kk * 32 + lk) >> 3;
        const f16x8 kf = *(const f16x8*)(Kl + (row * 8 + ((x ^ row) & 7)) * 8);
        a = __builtin_amdgcn_mfma_f32_16x16x32_f16(kk ? qf1 : qf0, kf, a, 0, 0, 0);
      }
#pragma unroll
      for (int r = 0; r < 4; ++r)
        sv[cb][r] = (mrow[r] == 0) ? -10000.f : a[r] * 0.125f;
    }

    // online softmax (wave-parallel: rows live in 16-lane groups)
#pragma unroll
    for (int r = 0; r < 4; ++r) {
      float tm = fmaxf(fmaxf(sv[0][r], sv[1][r]), fmaxf(sv[2][r], sv[3][r]));
#pragma unroll
      for (int off = 1; off < 16; off <<= 1)
        tm = fmaxf(tm, __shfl_xor(tm, off));
      const float newm  = fmaxf(m_run[r], tm);
      const float alpha = __expf(m_run[r] - newm);
      float ts = 0.f;
#pragma unroll
      for (int cb = 0; cb < 4; ++cb) {
        const float pe = __expf(sv[cb][r] - newm);
        sv[cb][r] = pe;
        ts += pe;
      }
#pragma unroll
      for (int off = 1; off < 16; off <<= 1)
        ts += __shfl_xor(ts, off);
      l_run[r] = l_run[r] * alpha + ts;
      m_run[r] = newm;
#pragma unroll
      for (int db = 0; db < 4; ++db)
        ctx[db][r] *= alpha;
    }

    // P -> LDS (per-wave buffer), then PV
#pragma unroll
    for (int cb = 0; cb < 4; ++cb)
#pragma unroll
      for (int r = 0; r < 4; ++r)
        Pl[w][(l >> 4) * 4 + r][cb * 16 + lr] = (f16)sv[cb][r];
    asm volatile("s_waitcnt lgkmcnt(0)" ::: "memory");
    __builtin_amdgcn_sched_barrier(0);

#pragma unroll
    for (int db = 0; db < 4; ++db) {
#pragma unroll
      for (int kk = 0; kk < 2; ++kk) {
        const f16x8 pf = *(const f16x8*)(&Pl[w][lr][kk * 32 + lk]);
        const int row = db * 16 + lr;
        const int x   = (kk * 32 + lk) >> 3;
        const f16x8 vf = *(const f16x8*)(Vl + (row * 8 + ((x ^ row) & 7)) * 8);
        ctx[db] = __builtin_amdgcn_mfma_f32_16x16x32_f16(pf, vf, ctx[db], 0, 0, 0);
      }
    }
    __syncthreads();
  }

#pragma unroll
  for (int db = 0; db < 4; ++db)
#pragma unroll
    for (int r = 0; r < 4; ++r) {
      const int qrow = qt * 64 + w * 16 + (l >> 4) * 4 + r;
      Out[(size_t)(b * S_ + qrow) * 1024 + h * 64 + db * 16 + lr] = ctx[db][r] / l_run[r];
    }
}

extern "C" void kernel_launch(void* const* d_in, const int* in_sizes, int n_in,
                              void* d_out, int out_size, void* d_ws, size_t ws_size,
                              hipStream_t stream) {
  const float* hs = (const float*)d_in[0];
  const float* Wq = (const float*)d_in[1];
  const float* bq = (const float*)d_in[2];
  const float* Wk = (const float*)d_in[3];
  const float* bk = (const float*)d_in[4];
  const float* Wv = (const float*)d_in[5];
  const float* bv = (const float*)d_in[6];
  const int* mask = (const int*)d_in[7];
  float* out = (float*)d_out;

  // workspace carve-up (f16 units): 102 MB total
  f16* hsF  = (f16*)d_ws;                       // 8192*1024
  f16* wF   = hsF + (size_t)M_ * HID_;          // 3*1024*1024
  f16* qF   = wF + 3ull * HID_ * HID_;          // 8192*1024
  f16* kF   = qF + (size_t)M_ * HID_;           // 8192*1024
  f16* vF   = kF + (size_t)M_ * HID_;           // 8192*1024
  f16* keff = vF + (size_t)M_ * HID_;           // 64*2048*64
  f16* vt   = keff + (size_t)M_ * HID_;         // 64*64*2048

  cvt_f32_f16_k<<<dim3((M_ * HID_) / 1024), 256, 0, stream>>>(hs, hsF, (M_ * HID_) / 4);
  cvt_f32_f16_k<<<dim3((HID_ * HID_) / 1024), 256, 0, stream>>>(Wq, wF, (HID_ * HID_) / 4);
  cvt_f32_f16_k<<<dim3((HID_ * HID_) / 1024), 256, 0, stream>>>(Wk, wF + (size_t)HID_ * HID_, (HID_ * HID_) / 4);
  cvt_f32_f16_k<<<dim3((HID_ * HID_) / 1024), 256, 0, stream>>>(Wv, wF + 2ull * (size_t)HID_ * HID_, (HID_ * HID_) / 4);

  proj_gemm_k<<<dim3(24, 64), 256, 0, stream>>>(hsF, wF, bq, bk, bv, qF);
  prep_kv_k<<<dim3(64, 32), 256, 0, stream>>>(kF, vF, keff, vt);
  attn_k<<<dim3(64, 32), 256, 0, stream>>>(qF, keff, vt, mask, out);
}

// Round 5
// 234.023 us; speedup vs baseline: 1.2844x; 1.2844x over previous
//
#include <hip/hip_runtime.h>
#include <hip/hip_fp16.h>
#include <cstdint>

#define B_   4
#define S_   2048
#define HID_ 1024
#define NH_  16
#define HD_  64
#define M_   (B_ * S_)   // 8192

using f16   = _Float16;
using f16x4 = __attribute__((ext_vector_type(4))) _Float16;
using f16x8 = __attribute__((ext_vector_type(8))) _Float16;
using f32x4 = __attribute__((ext_vector_type(4))) float;

// async 16B global -> LDS (HW writes wave-uniform base + lane*16)
__device__ __forceinline__ void g2lds16(const void* g, void* l) {
  __builtin_amdgcn_global_load_lds(
      (__attribute__((address_space(1))) void*)(uintptr_t)g,
      (__attribute__((address_space(3))) void*)(uint32_t)(uintptr_t)l,
      16, 0, 0);
}

// ---------------- f32 -> f16 convert ----------------
__global__ void cvt_f32_f16_k(const float* __restrict__ src, f16* __restrict__ dst, int n4) {
  int i = blockIdx.x * blockDim.x + threadIdx.x;
  if (i >= n4) return;
  float4 v = ((const float4*)src)[i];
  f16x4 h;
  h[0] = (f16)v.x; h[1] = (f16)v.y; h[2] = (f16)v.z; h[3] = (f16)v.w;
  ((f16x4*)dst)[i] = h;
}

// ---------------- fused QKV projection GEMM ----------------
__global__ __launch_bounds__(256) void proj_gemm_k(
    const f16* __restrict__ A, const f16* __restrict__ W,
    const float* __restrict__ bq, const float* __restrict__ bk, const float* __restrict__ bv,
    f16* __restrict__ Out) {
  __shared__ __align__(16) f16 As[128 * 64];
  __shared__ __align__(16) f16 Bs[128 * 64];
  const int tid = threadIdx.x;
  const int l   = tid & 63;
  const int w   = tid >> 6;
  const int lr  = l & 15;
  const int lk  = (l >> 4) * 8;
  const int col0 = blockIdx.x * 128;
  const int row0 = blockIdx.y * 128;
  const int wr = (w >> 1) * 64;
  const int wc = (w & 1) * 64;

  f32x4 acc[4][4] = {};

  for (int kt = 0; kt < 16; ++kt) {
    const int k0 = kt * 64;
#pragma unroll
    for (int i = 0; i < 4; ++i) {
      const int c   = tid + i * 256;
      const int row = c >> 3;
      const int cb  = (c ^ row) & 7;
      g2lds16(A + (size_t)(row0 + row) * 1024 + k0 + cb * 8,
              As + (w * 64 + i * 256) * 8);
      g2lds16(W + (size_t)(col0 + row) * 1024 + k0 + cb * 8,
              Bs + (w * 64 + i * 256) * 8);
    }
    asm volatile("s_waitcnt vmcnt(0)" ::: "memory");
    __syncthreads();

#pragma unroll
    for (int kk = 0; kk < 64; kk += 32) {
      const int x = (kk + lk) >> 3;
      f16x8 af[4], bf[4];
#pragma unroll
      for (int m = 0; m < 4; ++m) {
        const int row = wr + m * 16 + lr;
        af[m] = *(const f16x8*)(As + (row * 8 + ((x ^ row) & 7)) * 8);
      }
#pragma unroll
      for (int n = 0; n < 4; ++n) {
        const int row = wc + n * 16 + lr;
        bf[n] = *(const f16x8*)(Bs + (row * 8 + ((x ^ row) & 7)) * 8);
      }
#pragma unroll
      for (int m = 0; m < 4; ++m)
#pragma unroll
        for (int n = 0; n < 4; ++n)
          acc[m][n] = __builtin_amdgcn_mfma_f32_16x16x32_f16(af[m], bf[n], acc[m][n], 0, 0, 0);
    }
    __syncthreads();
  }

  const int proj = col0 >> 10;
  const float* bias = (proj == 0) ? bq : ((proj == 1) ? bk : bv);
  f16* outp = Out + (size_t)proj * ((size_t)M_ * HID_);
#pragma unroll
  for (int n = 0; n < 4; ++n) {
    const int col = col0 + wc + n * 16 + lr;
    const int cp  = col & 1023;
    const float bb = bias[cp];
#pragma unroll
    for (int m = 0; m < 4; ++m) {
      const int rbase = row0 + wr + m * 16 + (l >> 4) * 4;
#pragma unroll
      for (int r = 0; r < 4; ++r)
        outp[(size_t)(rbase + r) * 1024 + cp] = (f16)(acc[m][n][r] + bb);
    }
  }
}

// ---------------- keff + V-transpose prep ----------------
__global__ __launch_bounds__(256) void prep_kv_k(
    const f16* __restrict__ Kp, const f16* __restrict__ Vp,
    f16* __restrict__ Keff, f16* __restrict__ Vt) {
  const int bh = blockIdx.x;  // 64
  const int st = blockIdx.y;  // 32
  const int b = bh >> 4, h = bh & 15;
  const int tid = threadIdx.x;
#pragma unroll
  for (int i = 0; i < 2; ++i) {
    const int c  = tid + i * 256;
    const int sl = c >> 3, cb = c & 7;
    const int s  = st * 64 + sl;
    const size_t src = (size_t)(b * S_ + s) * 1024 + h * 64 + cb * 8;
    const f16x8 kv = *(const f16x8*)(Kp + src);
    const f16x8 vv = *(const f16x8*)(Vp + src);
    f16x8 ke;
#pragma unroll
    for (int j = 0; j < 8; ++j) {
      const float kf = (float)kv[j], vf = (float)vv[j];
      const float s1 = kf / (1.f + fabsf(kf));
      const float t  = s1 * 0.125f;
      const float s2 = t / (1.f + fabsf(t));
      ke[j] = (f16)(kf * 0.125f + s2 + vf);
    }
    *(f16x8*)(Keff + ((size_t)bh * S_ + s) * 64 + cb * 8) = ke;
#pragma unroll
    for (int j = 0; j < 8; ++j)
      Vt[((size_t)bh * 64 + cb * 8 + j) * S_ + s] = vv[j];
  }
}

// ---------------- flash attention (R1-validated mappings, 32q/wave, no-max SM) ----
// block = (bh, qtile of 128 rows), 4 waves x 32 q-rows (qb=0,1); K/V tiles 64, dbuf.
// QK: mfma(qf, kf): D -> S[q = g*4+r][key = cb*16+lr]          (R1-validated)
// P:  Pl[w][qb][q][key], scalar f16 stores (D-layout direct)    (R1-validated)
// PV: pf = Pl[w][qb][q=lr][keys kk*32+g*8..+7], mfma(pf, vf)    (R1-validated)
// No max-tracking: pe = exp2(dot*C - 8), shift cancels in the division;
// row-sum deferred to epilogue (sum is linear without rescaling).
__global__ __launch_bounds__(256) void attn_k(
    const f16* __restrict__ Q,     // [8192][1024]
    const f16* __restrict__ Keff,  // [64][2048][64]
    const f16* __restrict__ Vt,    // [64][64][2048]
    const int* __restrict__ mask,  // [4][2048]
    float* __restrict__ Out) {     // [8192][1024] f32
  __shared__ __align__(16) f16 Kl[2][64 * 64];
  __shared__ __align__(16) f16 Vl[2][64 * 64];
  __shared__ __align__(16) f16 Pl[4][2][16][72];  // [wave][qb][q][key(+8 pad)]
  const int bh = blockIdx.x, qt = blockIdx.y;
  const int b = bh >> 4, h = bh & 15;
  const int tid = threadIdx.x;
  const int l = tid & 63, w = tid >> 6;
  const int lr = l & 15, g = l >> 4;
  const float C = 0.180336880111120426f;  // 0.125 * log2(e)

  // Q fragments (A-operand): lane(g,lr) holds Q[qrow(lr)][kk*32 + g*8 .. +7];
  // zeroed if q-row masked (-> uniform P = reference's masked-row semantics).
  f16x8 qf[2][2];
#pragma unroll
  for (int qb = 0; qb < 2; ++qb) {
    const int qrow = qt * 128 + w * 32 + qb * 16 + lr;
    const f16* qs = Q + (size_t)(b * S_ + qrow) * 1024 + h * 64 + g * 8;
    qf[qb][0] = *(const f16x8*)(qs);
    qf[qb][1] = *(const f16x8*)(qs + 32);
    if (mask[b * S_ + qrow] == 0) {
      qf[qb][0] = (f16x8)(f16)0;
      qf[qb][1] = (f16x8)(f16)0;
    }
  }

  f32x4 ctx[2][4] = {};
  f32x4 lacc[2] = {};

#define STAGE(bf, kt2)                                                         \
  {                                                                            \
    _Pragma("unroll") for (int i = 0; i < 2; ++i) {                            \
      const int n = tid + i * 256;                                             \
      const int row = n >> 3, cl = n & 7;                                      \
      const int c = cl ^ (row & 7);                                            \
      g2lds16(Keff + ((size_t)bh * S_ + (kt2) * 64 + row) * 64 + c * 8,        \
              &Kl[bf][(w * 64 + i * 256) * 8]);                                \
      g2lds16(Vt + ((size_t)bh * 64 + row) * 2048 + (kt2) * 64 + c * 8,        \
              &Vl[bf][(w * 64 + i * 256) * 8]);                                \
    }                                                                          \
  }

  STAGE(0, 0);
  asm volatile("s_waitcnt vmcnt(0)" ::: "memory");
  __syncthreads();

  for (int kt = 0; kt < 32; ++kt) {
    const int cur = kt & 1;
    if (kt < 31) STAGE(cur ^ 1, kt + 1);

    // ---- QK: sv[qb][cb][r] = S[q = g*4+r][key = cb*16+lr] ----
    f32x4 sv[2][4] = {};
#pragma unroll
    for (int kk = 0; kk < 2; ++kk)
#pragma unroll
      for (int cb = 0; cb < 4; ++cb) {
        const int row = cb * 16 + lr;
        const f16x8 kf = *(const f16x8*)(&Kl[cur][(row * 8 + ((kk * 4 + g) ^ (row & 7))) * 8]);
        sv[0][cb] = __builtin_amdgcn_mfma_f32_16x16x32_f16(qf[0][kk], kf, sv[0][cb], 0, 0, 0);
        sv[1][cb] = __builtin_amdgcn_mfma_f32_16x16x32_f16(qf[1][kk], kf, sv[1][cb], 0, 0, 0);
      }

    // ---- softmax-lite: pe = exp2(dot*C - 8); accumulate row-sum in-lane;
    //      scalar f16 stores to wave-private P (R1 pattern) ----
#pragma unroll
    for (int qb = 0; qb < 2; ++qb) {
      f32x4 pv[4];
#pragma unroll
      for (int cb = 0; cb < 4; ++cb)
#pragma unroll
        for (int r = 0; r < 4; ++r)
          pv[cb][r] = exp2f(fmaf(sv[qb][cb][r], C, -8.0f));
      lacc[qb] += (pv[0] + pv[1]) + (pv[2] + pv[3]);
#pragma unroll
      for (int cb = 0; cb < 4; ++cb)
#pragma unroll
        for (int r = 0; r < 4; ++r)
          Pl[w][qb][g * 4 + r][cb * 16 + lr] = (f16)pv[cb][r];
    }
    asm volatile("s_waitcnt lgkmcnt(0)" ::: "memory");
    __builtin_amdgcn_sched_barrier(0);

    // ---- PV: pf = P[q=lr][keys kk*32+g*8..+7]; ctx[qb][db] += pf x vf ----
#pragma unroll
    for (int kk = 0; kk < 2; ++kk) {
      const f16x8 pf0 = *(const f16x8*)(&Pl[w][0][lr][kk * 32 + g * 8]);
      const f16x8 pf1 = *(const f16x8*)(&Pl[w][1][lr][kk * 32 + g * 8]);
#pragma unroll
      for (int db = 0; db < 4; ++db) {
        const int row = db * 16 + lr;
        const f16x8 vf = *(const f16x8*)(&Vl[cur][(row * 8 + ((kk * 4 + g) ^ (row & 7))) * 8]);
        ctx[0][db] = __builtin_amdgcn_mfma_f32_16x16x32_f16(pf0, vf, ctx[0][db], 0, 0, 0);
        ctx[1][db] = __builtin_amdgcn_mfma_f32_16x16x32_f16(pf1, vf, ctx[1][db], 0, 0, 0);
      }
    }

    asm volatile("s_waitcnt vmcnt(0)" ::: "memory");
    __syncthreads();
  }

  // ---- epilogue: 16-lane row-sum reduce (once), divide, store (R1 pattern) ----
#pragma unroll
  for (int qb = 0; qb < 2; ++qb) {
    f32x4 ls = lacc[qb];
#pragma unroll
    for (int off = 1; off < 16; off <<= 1)
#pragma unroll
      for (int r = 0; r < 4; ++r)
        ls[r] += __shfl_xor(ls[r], off);
    f32x4 linv;
#pragma unroll
    for (int r = 0; r < 4; ++r) linv[r] = 1.0f / ls[r];
#pragma unroll
    for (int db = 0; db < 4; ++db)
#pragma unroll
      for (int r = 0; r < 4; ++r) {
        const int qrow = qt * 128 + w * 32 + qb * 16 + g * 4 + r;
        Out[(size_t)(b * S_ + qrow) * 1024 + h * 64 + db * 16 + lr] =
            ctx[qb][db][r] * linv[r];
      }
  }
}

extern "C" void kernel_launch(void* const* d_in, const int* in_sizes, int n_in,
                              void* d_out, int out_size, void* d_ws, size_t ws_size,
                              hipStream_t stream) {
  const float* hs = (const float*)d_in[0];
  const float* Wq = (const float*)d_in[1];
  const float* bq = (const float*)d_in[2];
  const float* Wk = (const float*)d_in[3];
  const float* bk = (const float*)d_in[4];
  const float* Wv = (const float*)d_in[5];
  const float* bv = (const float*)d_in[6];
  const int* mask = (const int*)d_in[7];
  float* out = (float*)d_out;

  f16* hsF  = (f16*)d_ws;                       // 8192*1024
  f16* wF   = hsF + (size_t)M_ * HID_;          // 3*1024*1024
  f16* qF   = wF + 3ull * HID_ * HID_;          // 8192*1024
  f16* kF   = qF + (size_t)M_ * HID_;           // 8192*1024
  f16* vF   = kF + (size_t)M_ * HID_;           // 8192*1024
  f16* keff = vF + (size_t)M_ * HID_;           // 64*2048*64
  f16* vt   = keff + (size_t)M_ * HID_;         // 64*64*2048

  cvt_f32_f16_k<<<dim3((M_ * HID_) / 1024), 256, 0, stream>>>(hs, hsF, (M_ * HID_) / 4);
  cvt_f32_f16_k<<<dim3((HID_ * HID_) / 1024), 256, 0, stream>>>(Wq, wF, (HID_ * HID_) / 4);
  cvt_f32_f16_k<<<dim3((HID_ * HID_) / 1024), 256, 0, stream>>>(Wk, wF + (size_t)HID_ * HID_, (HID_ * HID_) / 4);
  cvt_f32_f16_k<<<dim3((HID_ * HID_) / 1024), 256, 0, stream>>>(Wv, wF + 2ull * (size_t)HID_ * HID_, (HID_ * HID_) / 4);

  proj_gemm_k<<<dim3(24, 64), 256, 0, stream>>>(hsF, wF, bq, bk, bv, qF);
  prep_kv_k<<<dim3(64, 32), 256, 0, stream>>>(kF, vF, keff, vt);
  attn_k<<<dim3(64, 16), 256, 0, stream>>>(qF, keff, vt, mask, out);
}

// Round 6
// 206.956 us; speedup vs baseline: 1.4524x; 1.1308x over previous
//
#include <hip/hip_runtime.h>
#include <hip/hip_fp16.h>
#include <cstdint>

#define B_   4
#define S_   2048
#define HID_ 1024
#define NH_  16
#define HD_  64
#define M_   (B_ * S_)   // 8192

using f16   = _Float16;
using f16x4 = __attribute__((ext_vector_type(4))) _Float16;
using f16x8 = __attribute__((ext_vector_type(8))) _Float16;
using f32x4 = __attribute__((ext_vector_type(4))) float;
using u32x4 = __attribute__((ext_vector_type(4))) unsigned int;

// async 16B global -> LDS (HW writes wave-uniform base + lane*16)
__device__ __forceinline__ void g2lds16(const void* g, void* l) {
  __builtin_amdgcn_global_load_lds(
      (__attribute__((address_space(1))) void*)(uintptr_t)g,
      (__attribute__((address_space(3))) void*)(uint32_t)(uintptr_t)l,
      16, 0, 0);
}

// pack 2 f32 -> 2 f16 in one u32 (round-to-zero): src0 -> lo16, src1 -> hi16
__device__ __forceinline__ unsigned int pk16(float a, float b) {
  unsigned int r;
  asm("v_cvt_pkrtz_f16_f32 %0, %1, %2" : "=v"(r) : "v"(a), "v"(b));
  return r;
}

// key permutation for K-staging: bit shuffle [c1 c0 g1 g0 r1 r0] -> [c1 g1 g0 c0 r1 r0]
// so that QK D-rows (g*4+r per 16-row tile cb) land on true keys kk*32+g*8+(cb&1)*4+r.
#define PIDX(r) (((r) & 32) | (((r) & 12) << 1) | ((((r) >> 4) & 1) << 2) | ((r) & 3))

// ---------------- f32 -> f16 convert ----------------
__global__ void cvt_f32_f16_k(const float* __restrict__ src, f16* __restrict__ dst, int n4) {
  int i = blockIdx.x * blockDim.x + threadIdx.x;
  if (i >= n4) return;
  float4 v = ((const float4*)src)[i];
  f16x4 h;
  h[0] = (f16)v.x; h[1] = (f16)v.y; h[2] = (f16)v.z; h[3] = (f16)v.w;
  ((f16x4*)dst)[i] = h;
}

// ---------------- fused QKV projection GEMM ----------------
__global__ __launch_bounds__(256) void proj_gemm_k(
    const f16* __restrict__ A, const f16* __restrict__ W,
    const float* __restrict__ bq, const float* __restrict__ bk, const float* __restrict__ bv,
    f16* __restrict__ Out) {
  __shared__ __align__(16) f16 As[128 * 64];
  __shared__ __align__(16) f16 Bs[128 * 64];
  const int tid = threadIdx.x;
  const int l   = tid & 63;
  const int w   = tid >> 6;
  const int lr  = l & 15;
  const int lk  = (l >> 4) * 8;
  const int col0 = blockIdx.x * 128;
  const int row0 = blockIdx.y * 128;
  const int wr = (w >> 1) * 64;
  const int wc = (w & 1) * 64;

  f32x4 acc[4][4] = {};

  for (int kt = 0; kt < 16; ++kt) {
    const int k0 = kt * 64;
#pragma unroll
    for (int i = 0; i < 4; ++i) {
      const int c   = tid + i * 256;
      const int row = c >> 3;
      const int cb  = (c ^ row) & 7;
      g2lds16(A + (size_t)(row0 + row) * 1024 + k0 + cb * 8,
              As + (w * 64 + i * 256) * 8);
      g2lds16(W + (size_t)(col0 + row) * 1024 + k0 + cb * 8,
              Bs + (w * 64 + i * 256) * 8);
    }
    asm volatile("s_waitcnt vmcnt(0)" ::: "memory");
    __syncthreads();

#pragma unroll
    for (int kk = 0; kk < 64; kk += 32) {
      const int x = (kk + lk) >> 3;
      f16x8 af[4], bf[4];
#pragma unroll
      for (int m = 0; m < 4; ++m) {
        const int row = wr + m * 16 + lr;
        af[m] = *(const f16x8*)(As + (row * 8 + ((x ^ row) & 7)) * 8);
      }
#pragma unroll
      for (int n = 0; n < 4; ++n) {
        const int row = wc + n * 16 + lr;
        bf[n] = *(const f16x8*)(Bs + (row * 8 + ((x ^ row) & 7)) * 8);
      }
#pragma unroll
      for (int m = 0; m < 4; ++m)
#pragma unroll
        for (int n = 0; n < 4; ++n)
          acc[m][n] = __builtin_amdgcn_mfma_f32_16x16x32_f16(af[m], bf[n], acc[m][n], 0, 0, 0);
    }
    __syncthreads();
  }

  const int proj = col0 >> 10;
  const float* bias = (proj == 0) ? bq : ((proj == 1) ? bk : bv);
  f16* outp = Out + (size_t)proj * ((size_t)M_ * HID_);
#pragma unroll
  for (int n = 0; n < 4; ++n) {
    const int col = col0 + wc + n * 16 + lr;
    const int cp  = col & 1023;
    const float bb = bias[cp];
#pragma unroll
    for (int m = 0; m < 4; ++m) {
      const int rbase = row0 + wr + m * 16 + (l >> 4) * 4;
#pragma unroll
      for (int r = 0; r < 4; ++r)
        outp[(size_t)(rbase + r) * 1024 + cp] = (f16)(acc[m][n][r] + bb);
    }
  }
}

// ---------------- keff + V-transpose prep ----------------
__global__ __launch_bounds__(256) void prep_kv_k(
    const f16* __restrict__ Kp, const f16* __restrict__ Vp,
    f16* __restrict__ Keff, f16* __restrict__ Vt) {
  const int bh = blockIdx.x;  // 64
  const int st = blockIdx.y;  // 32
  const int b = bh >> 4, h = bh & 15;
  const int tid = threadIdx.x;
#pragma unroll
  for (int i = 0; i < 2; ++i) {
    const int c  = tid + i * 256;
    const int sl = c >> 3, cb = c & 7;
    const int s  = st * 64 + sl;
    const size_t src = (size_t)(b * S_ + s) * 1024 + h * 64 + cb * 8;
    const f16x8 kv = *(const f16x8*)(Kp + src);
    const f16x8 vv = *(const f16x8*)(Vp + src);
    f16x8 ke;
#pragma unroll
    for (int j = 0; j < 8; ++j) {
      const float kf = (float)kv[j], vf = (float)vv[j];
      const float s1 = kf / (1.f + fabsf(kf));
      const float t  = s1 * 0.125f;
      const float s2 = t / (1.f + fabsf(t));
      ke[j] = (f16)(kf * 0.125f + s2 + vf);
    }
    *(f16x8*)(Keff + ((size_t)bh * S_ + s) * 64 + cb * 8) = ke;
#pragma unroll
    for (int j = 0; j < 8; ++j)
      Vt[((size_t)bh * 64 + cb * 8 + j) * S_ + s] = vv[j];
  }
}

// ---------------- flash attention (swapped QK + pi-staged K, P fully in registers) --
// block = (bh, qtile of 128 rows), 4 waves x 32 q-rows (qb=0,1); K/V tiles 64, dbuf.
// K staged with row-permutation PIDX: QK mfma(kf, qf) leaves lane (g,lr) holding
// P[q=lr][true keys kk*32+g*8+(cb&1)*4+r] -> PV B-fragment assembled IN-LANE via
// v_cvt_pkrtz (no LDS round-trip, no permlane). Vl stays in true-key order.
// No max-tracking: pe = exp2(dot*C - 8); shift cancels in the division.
__global__ __launch_bounds__(256) void attn_k(
    const f16* __restrict__ Q,     // [8192][1024]
    const f16* __restrict__ Keff,  // [64][2048][64]
    const f16* __restrict__ Vt,    // [64][64][2048]
    const int* __restrict__ mask,  // [4][2048]
    float* __restrict__ Out) {     // [8192][1024] f32
  __shared__ __align__(16) f16 Kl[2][64 * 64];
  __shared__ __align__(16) f16 Vl[2][64 * 64];
  const int bh = blockIdx.x, qt = blockIdx.y;
  const int b = bh >> 4, h = bh & 15;
  const int tid = threadIdx.x;
  const int l = tid & 63, w = tid >> 6;
  const int lr = l & 15, g = l >> 4;
  const float C = 0.180336880111120426f;  // 0.125 * log2(e)

  // Q fragments (B-operand of mfma(kf,qf)): lane (g,lr) holds
  // Q[qrow(lr)][kk*32 + g*8 .. +7]; zeroed if q-row masked.
  f16x8 qf[2][2];
#pragma unroll
  for (int qb = 0; qb < 2; ++qb) {
    const int qrow = qt * 128 + w * 32 + qb * 16 + lr;
    const f16* qs = Q + (size_t)(b * S_ + qrow) * 1024 + h * 64 + g * 8;
    qf[qb][0] = *(const f16x8*)(qs);
    qf[qb][1] = *(const f16x8*)(qs + 32);
    if (mask[b * S_ + qrow] == 0) {
      qf[qb][0] = (f16x8)(f16)0;
      qf[qb][1] = (f16x8)(f16)0;
    }
  }

  f32x4 ctx[2][4] = {};          // ctx[qb][db][r] = O[q=lr][d=db*16+g*4+r]
  float lacc[2] = {0.f, 0.f};

  // stage tile kt: K rows permuted by PIDX, V in true-key order; XOR chunk swizzle.
#define STAGE(bf, kt2)                                                         \
  {                                                                            \
    _Pragma("unroll") for (int i = 0; i < 2; ++i) {                            \
      const int n = tid + i * 256;                                             \
      const int row = n >> 3, cl = n & 7;                                      \
      const int c = cl ^ (row & 7);                                            \
      g2lds16(Keff + ((size_t)bh * S_ + (kt2) * 64 + PIDX(row)) * 64 + c * 8,  \
              &Kl[bf][(w * 64 + i * 256) * 8]);                                \
      g2lds16(Vt + ((size_t)bh * 64 + row) * 2048 + (kt2) * 64 + c * 8,        \
              &Vl[bf][(w * 64 + i * 256) * 8]);                                \
    }                                                                          \
  }

  STAGE(0, 0);
  asm volatile("s_waitcnt vmcnt(0)" ::: "memory");
  __syncthreads();

  for (int kt = 0; kt < 32; ++kt) {
    const int cur = kt & 1;
    if (kt < 31) STAGE(cur ^ 1, kt + 1);

    // ---- QK (swapped): sv[qb][cb][r] = S[key=pi(cb*16+g*4+r)][q=lr] ----
    f32x4 sv[2][4] = {};
#pragma unroll
    for (int kk = 0; kk < 2; ++kk)
#pragma unroll
      for (int cb = 0; cb < 4; ++cb) {
        const int row = cb * 16 + lr;
        const f16x8 kf = *(const f16x8*)(&Kl[cur][(row * 8 + ((kk * 4 + g) ^ (row & 7))) * 8]);
        sv[0][cb] = __builtin_amdgcn_mfma_f32_16x16x32_f16(kf, qf[0][kk], sv[0][cb], 0, 0, 0);
        sv[1][cb] = __builtin_amdgcn_mfma_f32_16x16x32_f16(kf, qf[1][kk], sv[1][cb], 0, 0, 0);
      }

    // ---- softmax-lite: pe = exp2(dot*C - 8); in-lane partial row-sum ----
    float pv[2][4][4];
#pragma unroll
    for (int qb = 0; qb < 2; ++qb) {
      float s = 0.f;
#pragma unroll
      for (int cb = 0; cb < 4; ++cb)
#pragma unroll
        for (int r = 0; r < 4; ++r) {
          const float pe = exp2f(fmaf(sv[qb][cb][r], C, -8.0f));
          pv[qb][cb][r] = pe;
          s += pe;
        }
      lacc[qb] += s;
    }

    // ---- PV: pf assembled in-lane (true keys kk*32+g*8..+7), mfma(vf, pf) ----
#pragma unroll
    for (int kk = 0; kk < 2; ++kk) {
      f16x8 pf[2];
#pragma unroll
      for (int qb = 0; qb < 2; ++qb) {
        u32x4 pw = {pk16(pv[qb][2 * kk][0], pv[qb][2 * kk][1]),
                    pk16(pv[qb][2 * kk][2], pv[qb][2 * kk][3]),
                    pk16(pv[qb][2 * kk + 1][0], pv[qb][2 * kk + 1][1]),
                    pk16(pv[qb][2 * kk + 1][2], pv[qb][2 * kk + 1][3])};
        pf[qb] = __builtin_bit_cast(f16x8, pw);
      }
#pragma unroll
      for (int db = 0; db < 4; ++db) {
        const int row = db * 16 + lr;
        const f16x8 vf = *(const f16x8*)(&Vl[cur][(row * 8 + ((kk * 4 + g) ^ (row & 7))) * 8]);
        ctx[0][db] = __builtin_amdgcn_mfma_f32_16x16x32_f16(vf, pf[0], ctx[0][db], 0, 0, 0);
        ctx[1][db] = __builtin_amdgcn_mfma_f32_16x16x32_f16(vf, pf[1], ctx[1][db], 0, 0, 0);
      }
    }

    asm volatile("s_waitcnt vmcnt(0)" ::: "memory");
    __syncthreads();
  }

  // ---- finalize: sum lacc over the 4 g-groups (shfl), divide, store f32x4 ----
#pragma unroll
  for (int qb = 0; qb < 2; ++qb) {
    float ls = lacc[qb];
    ls += __shfl_xor(ls, 16);
    ls += __shfl_xor(ls, 32);
    const float linv = 1.0f / ls;
    const int qrow = qt * 128 + w * 32 + qb * 16 + lr;
    float* op = Out + (size_t)(b * S_ + qrow) * 1024 + h * 64 + g * 4;
#pragma unroll
    for (int db = 0; db < 4; ++db) {
      f32x4 o = ctx[qb][db] * linv;
      *(f32x4*)(op + db * 16) = o;
    }
  }
}

extern "C" void kernel_launch(void* const* d_in, const int* in_sizes, int n_in,
                              void* d_out, int out_size, void* d_ws, size_t ws_size,
                              hipStream_t stream) {
  const float* hs = (const float*)d_in[0];
  const float* Wq = (const float*)d_in[1];
  const float* bq = (const float*)d_in[2];
  const float* Wk = (const float*)d_in[3];
  const float* bk = (const float*)d_in[4];
  const float* Wv = (const float*)d_in[5];
  const float* bv = (const float*)d_in[6];
  const int* mask = (const int*)d_in[7];
  float* out = (float*)d_out;

  f16* hsF  = (f16*)d_ws;                       // 8192*1024
  f16* wF   = hsF + (size_t)M_ * HID_;          // 3*1024*1024
  f16* qF   = wF + 3ull * HID_ * HID_;          // 8192*1024
  f16* kF   = qF + (size_t)M_ * HID_;           // 8192*1024
  f16* vF   = kF + (size_t)M_ * HID_;           // 8192*1024
  f16* keff = vF + (size_t)M_ * HID_;           // 64*2048*64
  f16* vt   = keff + (size_t)M_ * HID_;         // 64*64*2048

  cvt_f32_f16_k<<<dim3((M_ * HID_) / 1024), 256, 0, stream>>>(hs, hsF, (M_ * HID_) / 4);
  cvt_f32_f16_k<<<dim3((HID_ * HID_) / 1024), 256, 0, stream>>>(Wq, wF, (HID_ * HID_) / 4);
  cvt_f32_f16_k<<<dim3((HID_ * HID_) / 1024), 256, 0, stream>>>(Wk, wF + (size_t)HID_ * HID_, (HID_ * HID_) / 4);
  cvt_f32_f16_k<<<dim3((HID_ * HID_) / 1024), 256, 0, stream>>>(Wv, wF + 2ull * (size_t)HID_ * HID_, (HID_ * HID_) / 4);

  proj_gemm_k<<<dim3(24, 64), 256, 0, stream>>>(hsF, wF, bq, bk, bv, qF);
  prep_kv_k<<<dim3(64, 32), 256, 0, stream>>>(kF, vF, keff, vt);
  attn_k<<<dim3(64, 16), 256, 0, stream>>>(qF, keff, vt, mask, out);
}

// Round 7
// 205.987 us; speedup vs baseline: 1.4592x; 1.0047x over previous
//
#include <hip/hip_runtime.h>
#include <hip/hip_fp16.h>
#include <cstdint>

#define B_   4
#define S_   2048
#define HID_ 1024
#define NH_  16
#define HD_  64
#define M_   (B_ * S_)   // 8192

using f16   = _Float16;
using f16x4 = __attribute__((ext_vector_type(4))) _Float16;
using f16x8 = __attribute__((ext_vector_type(8))) _Float16;
using f32x4 = __attribute__((ext_vector_type(4))) float;
using u32x4 = __attribute__((ext_vector_type(4))) unsigned int;

// async 16B global -> LDS (HW writes wave-uniform base + lane*16)
__device__ __forceinline__ void g2lds16(const void* g, void* l) {
  __builtin_amdgcn_global_load_lds(
      (__attribute__((address_space(1))) void*)(uintptr_t)g,
      (__attribute__((address_space(3))) void*)(uint32_t)(uintptr_t)l,
      16, 0, 0);
}

// pack 2 f32 -> 2 f16 in one u32 (round-to-zero): src0 -> lo16, src1 -> hi16
__device__ __forceinline__ unsigned int pk16(float a, float b) {
  unsigned int r;
  asm("v_cvt_pkrtz_f16_f32 %0, %1, %2" : "=v"(r) : "v"(a), "v"(b));
  return r;
}

// key permutation for K-staging: bit shuffle [c1 c0 g1 g0 r1 r0] -> [c1 g1 g0 c0 r1 r0]
// so that QK D-rows land on true keys kk*32+g*8+(cb&1)*4+r.   (R6-validated)
#define PIDX(r) (((r) & 32) | (((r) & 12) << 1) | ((((r) >> 4) & 1) << 2) | ((r) & 3))

// ---------------- f32 -> f16 convert ----------------
__global__ void cvt_f32_f16_k(const float* __restrict__ src, f16* __restrict__ dst, int n4) {
  int i = blockIdx.x * blockDim.x + threadIdx.x;
  if (i >= n4) return;
  float4 v = ((const float4*)src)[i];
  f16x4 h;
  h[0] = (f16)v.x; h[1] = (f16)v.y; h[2] = (f16)v.z; h[3] = (f16)v.w;
  ((f16x4*)dst)[i] = h;
}

// ---------------- fused QKV projection GEMM ----------------
__global__ __launch_bounds__(256) void proj_gemm_k(
    const f16* __restrict__ A, const f16* __restrict__ W,
    const float* __restrict__ bq, const float* __restrict__ bk, const float* __restrict__ bv,
    f16* __restrict__ Out) {
  __shared__ __align__(16) f16 As[128 * 64];
  __shared__ __align__(16) f16 Bs[128 * 64];
  const int tid = threadIdx.x;
  const int l   = tid & 63;
  const int w   = tid >> 6;
  const int lr  = l & 15;
  const int lk  = (l >> 4) * 8;
  const int col0 = blockIdx.x * 128;
  const int row0 = blockIdx.y * 128;
  const int wr = (w >> 1) * 64;
  const int wc = (w & 1) * 64;

  f32x4 acc[4][4] = {};

  for (int kt = 0; kt < 16; ++kt) {
    const int k0 = kt * 64;
#pragma unroll
    for (int i = 0; i < 4; ++i) {
      const int c   = tid + i * 256;
      const int row = c >> 3;
      const int cb  = (c ^ row) & 7;
      g2lds16(A + (size_t)(row0 + row) * 1024 + k0 + cb * 8,
              As + (w * 64 + i * 256) * 8);
      g2lds16(W + (size_t)(col0 + row) * 1024 + k0 + cb * 8,
              Bs + (w * 64 + i * 256) * 8);
    }
    asm volatile("s_waitcnt vmcnt(0)" ::: "memory");
    __syncthreads();

#pragma unroll
    for (int kk = 0; kk < 64; kk += 32) {
      const int x = (kk + lk) >> 3;
      f16x8 af[4], bf[4];
#pragma unroll
      for (int m = 0; m < 4; ++m) {
        const int row = wr + m * 16 + lr;
        af[m] = *(const f16x8*)(As + (row * 8 + ((x ^ row) & 7)) * 8);
      }
#pragma unroll
      for (int n = 0; n < 4; ++n) {
        const int row = wc + n * 16 + lr;
        bf[n] = *(const f16x8*)(Bs + (row * 8 + ((x ^ row) & 7)) * 8);
      }
#pragma unroll
      for (int m = 0; m < 4; ++m)
#pragma unroll
        for (int n = 0; n < 4; ++n)
          acc[m][n] = __builtin_amdgcn_mfma_f32_16x16x32_f16(af[m], bf[n], acc[m][n], 0, 0, 0);
    }
    __syncthreads();
  }

  const int proj = col0 >> 10;
  const float* bias = (proj == 0) ? bq : ((proj == 1) ? bk : bv);
  f16* outp = Out + (size_t)proj * ((size_t)M_ * HID_);
#pragma unroll
  for (int n = 0; n < 4; ++n) {
    const int col = col0 + wc + n * 16 + lr;
    const int cp  = col & 1023;
    const float bb = bias[cp];
#pragma unroll
    for (int m = 0; m < 4; ++m) {
      const int rbase = row0 + wr + m * 16 + (l >> 4) * 4;
#pragma unroll
      for (int r = 0; r < 4; ++r)
        outp[(size_t)(rbase + r) * 1024 + cp] = (f16)(acc[m][n][r] + bb);
    }
  }
}

// ---------------- keff + V-transpose prep ----------------
__global__ __launch_bounds__(256) void prep_kv_k(
    const f16* __restrict__ Kp, const f16* __restrict__ Vp,
    f16* __restrict__ Keff, f16* __restrict__ Vt) {
  const int bh = blockIdx.x;  // 64
  const int st = blockIdx.y;  // 32
  const int b = bh >> 4, h = bh & 15;
  const int tid = threadIdx.x;
#pragma unroll
  for (int i = 0; i < 2; ++i) {
    const int c  = tid + i * 256;
    const int sl = c >> 3, cb = c & 7;
    const int s  = st * 64 + sl;
    const size_t src = (size_t)(b * S_ + s) * 1024 + h * 64 + cb * 8;
    const f16x8 kv = *(const f16x8*)(Kp + src);
    const f16x8 vv = *(const f16x8*)(Vp + src);
    f16x8 ke;
#pragma unroll
    for (int j = 0; j < 8; ++j) {
      const float kf = (float)kv[j], vf = (float)vv[j];
      const float s1 = kf / (1.f + fabsf(kf));
      const float t  = s1 * 0.125f;
      const float s2 = t / (1.f + fabsf(t));
      ke[j] = (f16)(kf * 0.125f + s2 + vf);
    }
    *(f16x8*)(Keff + ((size_t)bh * S_ + s) * 64 + cb * 8) = ke;
#pragma unroll
    for (int j = 0; j < 8; ++j)
      Vt[((size_t)bh * 64 + cb * 8 + j) * S_ + s] = vv[j];
  }
}

// ---------------- flash attention: 64 q-rows/wave, P in registers ----------------
// block = (bh, qtile of 128 rows), 2 waves x 64 q-rows (qb=0..3); K/V tiles 64, dbuf.
// Same validated mappings as R6 (swapped QK + PIDX-staged K, in-lane pk16 pack).
// Each kf/vf ds_read_b128 now feeds 4 MFMAs (was 2) -> DS pipe halved per FLOP.
__global__ __launch_bounds__(128, 2) void attn_k(
    const f16* __restrict__ Q,     // [8192][1024]
    const f16* __restrict__ Keff,  // [64][2048][64]
    const f16* __restrict__ Vt,    // [64][64][2048]
    const int* __restrict__ mask,  // [4][2048]
    float* __restrict__ Out) {     // [8192][1024] f32
  __shared__ __align__(16) f16 Kl[2][64 * 64];
  __shared__ __align__(16) f16 Vl[2][64 * 64];
  const int bh = blockIdx.x, qt = blockIdx.y;
  const int b = bh >> 4, h = bh & 15;
  const int tid = threadIdx.x;
  const int l = tid & 63, w = tid >> 6;   // w in {0,1}
  const int lr = l & 15, g = l >> 4;
  const float C = 0.180336880111120426f;  // 0.125 * log2(e)

  // Q fragments (B-operand of mfma(kf,qf)): lane (g,lr) holds
  // Q[qrow(lr)][kk*32 + g*8 .. +7]; zeroed if q-row masked.
  f16x8 qf[4][2];
#pragma unroll
  for (int qb = 0; qb < 4; ++qb) {
    const int qrow = qt * 128 + w * 64 + qb * 16 + lr;
    const f16* qs = Q + (size_t)(b * S_ + qrow) * 1024 + h * 64 + g * 8;
    qf[qb][0] = *(const f16x8*)(qs);
    qf[qb][1] = *(const f16x8*)(qs + 32);
    if (mask[b * S_ + qrow] == 0) {
      qf[qb][0] = (f16x8)(f16)0;
      qf[qb][1] = (f16x8)(f16)0;
    }
  }

  f32x4 ctx[4][4] = {};          // ctx[qb][db][r] = O[q=lr][d=db*16+g*4+r]
  float lacc[4] = {0.f, 0.f, 0.f, 0.f};

  // stage tile kt (128 threads): K rows PIDX-permuted, V true-key order; XOR swizzle.
#define STAGE(bf, kt2)                                                         \
  {                                                                            \
    _Pragma("unroll") for (int i = 0; i < 4; ++i) {                            \
      const int n = tid + i * 128;                                             \
      const int row = n >> 3, cl = n & 7;                                      \
      const int c = cl ^ (row & 7);                                            \
      g2lds16(Keff + ((size_t)bh * S_ + (kt2) * 64 + PIDX(row)) * 64 + c * 8,  \
              &Kl[bf][(w * 64 + i * 128) * 8]);                                \
      g2lds16(Vt + ((size_t)bh * 64 + row) * 2048 + (kt2) * 64 + c * 8,        \
              &Vl[bf][(w * 64 + i * 128) * 8]);                                \
    }                                                                          \
  }

  STAGE(0, 0);
  asm volatile("s_waitcnt vmcnt(0)" ::: "memory");
  __syncthreads();

  for (int kt = 0; kt < 32; ++kt) {
    const int cur = kt & 1;
    if (kt < 31) STAGE(cur ^ 1, kt + 1);

    // ---- QK + softmax-lite, processed in cb-pair slices to cap registers ----
    f16x8 pf[4][2];   // pf[qb][cbp]: P[q=lr][true keys cbp*32 + g*8 .. +7]
#pragma unroll
    for (int cbp = 0; cbp < 2; ++cbp) {
      f32x4 sv[4][2] = {};
      __builtin_amdgcn_s_setprio(1);
#pragma unroll
      for (int kk = 0; kk < 2; ++kk)
#pragma unroll
        for (int cc = 0; cc < 2; ++cc) {
          const int row = (cbp * 2 + cc) * 16 + lr;
          const f16x8 kf = *(const f16x8*)(&Kl[cur][(row * 8 + ((kk * 4 + g) ^ (row & 7))) * 8]);
#pragma unroll
          for (int qb = 0; qb < 4; ++qb)
            sv[qb][cc] = __builtin_amdgcn_mfma_f32_16x16x32_f16(kf, qf[qb][kk], sv[qb][cc], 0, 0, 0);
        }
      __builtin_amdgcn_s_setprio(0);
      // pe = exp2(dot*C - 8); in-lane partial row-sum; pack to PV B-fragment
#pragma unroll
      for (int qb = 0; qb < 4; ++qb) {
        float pv[2][4];
        float s = 0.f;
#pragma unroll
        for (int cc = 0; cc < 2; ++cc)
#pragma unroll
          for (int r = 0; r < 4; ++r) {
            const float pe = exp2f(fmaf(sv[qb][cc][r], C, -8.0f));
            pv[cc][r] = pe;
            s += pe;
          }
        lacc[qb] += s;
        u32x4 pw = {pk16(pv[0][0], pv[0][1]), pk16(pv[0][2], pv[0][3]),
                    pk16(pv[1][0], pv[1][1]), pk16(pv[1][2], pv[1][3])};
        pf[qb][cbp] = __builtin_bit_cast(f16x8, pw);
      }
    }

    // ---- PV: mfma(vf, pf) ----
    __builtin_amdgcn_s_setprio(1);
#pragma unroll
    for (int kk = 0; kk < 2; ++kk)
#pragma unroll
      for (int db = 0; db < 4; ++db) {
        const int row = db * 16 + lr;
        const f16x8 vf = *(const f16x8*)(&Vl[cur][(row * 8 + ((kk * 4 + g) ^ (row & 7))) * 8]);
#pragma unroll
        for (int qb = 0; qb < 4; ++qb)
          ctx[qb][db] = __builtin_amdgcn_mfma_f32_16x16x32_f16(vf, pf[qb][kk], ctx[qb][db], 0, 0, 0);
      }
    __builtin_amdgcn_s_setprio(0);

    asm volatile("s_waitcnt vmcnt(0)" ::: "memory");
    __syncthreads();
  }

  // ---- finalize: sum lacc over the 4 g-groups (shfl), divide, store f32x4 ----
#pragma unroll
  for (int qb = 0; qb < 4; ++qb) {
    float ls = lacc[qb];
    ls += __shfl_xor(ls, 16);
    ls += __shfl_xor(ls, 32);
    const float linv = 1.0f / ls;
    const int qrow = qt * 128 + w * 64 + qb * 16 + lr;
    float* op = Out + (size_t)(b * S_ + qrow) * 1024 + h * 64 + g * 4;
#pragma unroll
    for (int db = 0; db < 4; ++db) {
      f32x4 o = ctx[qb][db] * linv;
      *(f32x4*)(op + db * 16) = o;
    }
  }
}

extern "C" void kernel_launch(void* const* d_in, const int* in_sizes, int n_in,
                              void* d_out, int out_size, void* d_ws, size_t ws_size,
                              hipStream_t stream) {
  const float* hs = (const float*)d_in[0];
  const float* Wq = (const float*)d_in[1];
  const float* bq = (const float*)d_in[2];
  const float* Wk = (const float*)d_in[3];
  const float* bk = (const float*)d_in[4];
  const float* Wv = (const float*)d_in[5];
  const float* bv = (const float*)d_in[6];
  const int* mask = (const int*)d_in[7];
  float* out = (float*)d_out;

  f16* hsF  = (f16*)d_ws;                       // 8192*1024
  f16* wF   = hsF + (size_t)M_ * HID_;          // 3*1024*1024
  f16* qF   = wF + 3ull * HID_ * HID_;          // 8192*1024
  f16* kF   = qF + (size_t)M_ * HID_;           // 8192*1024
  f16* vF   = kF + (size_t)M_ * HID_;           // 8192*1024
  f16* keff = vF + (size_t)M_ * HID_;           // 64*2048*64
  f16* vt   = keff + (size_t)M_ * HID_;         // 64*64*2048

  cvt_f32_f16_k<<<dim3((M_ * HID_) / 1024), 256, 0, stream>>>(hs, hsF, (M_ * HID_) / 4);
  cvt_f32_f16_k<<<dim3((HID_ * HID_) / 1024), 256, 0, stream>>>(Wq, wF, (HID_ * HID_) / 4);
  cvt_f32_f16_k<<<dim3((HID_ * HID_) / 1024), 256, 0, stream>>>(Wk, wF + (size_t)HID_ * HID_, (HID_ * HID_) / 4);
  cvt_f32_f16_k<<<dim3((HID_ * HID_) / 1024), 256, 0, stream>>>(Wv, wF + 2ull * (size_t)HID_ * HID_, (HID_ * HID_) / 4);

  proj_gemm_k<<<dim3(24, 64), 256, 0, stream>>>(hsF, wF, bq, bk, bv, qF);
  prep_kv_k<<<dim3(64, 32), 256, 0, stream>>>(kF, vF, keff, vt);
  attn_k<<<dim3(64, 16), 128, 0, stream>>>(qF, keff, vt, mask, out);
}

// Round 9
// 202.708 us; speedup vs baseline: 1.4829x; 1.0162x over previous
//
#include <hip/hip_runtime.h>
#include <hip/hip_fp16.h>
#include <cstdint>

#define B_   4
#define S_   2048
#define HID_ 1024
#define NH_  16
#define HD_  64
#define M_   (B_ * S_)   // 8192

using f16   = _Float16;
using f16x4 = __attribute__((ext_vector_type(4))) _Float16;
using f16x8 = __attribute__((ext_vector_type(8))) _Float16;
using f32x4 = __attribute__((ext_vector_type(4))) float;
using u32x4 = __attribute__((ext_vector_type(4))) unsigned int;

// async 16B global -> LDS (HW writes wave-uniform base + lane*16)
__device__ __forceinline__ void g2lds16(const void* g, void* l) {
  __builtin_amdgcn_global_load_lds(
      (__attribute__((address_space(1))) void*)(uintptr_t)g,
      (__attribute__((address_space(3))) void*)(uint32_t)(uintptr_t)l,
      16, 0, 0);
}

// pack 2 f32 -> 2 f16 in one u32 (round-to-zero): src0 -> lo16, src1 -> hi16
__device__ __forceinline__ unsigned int pk16(float a, float b) {
  unsigned int r;
  asm("v_cvt_pkrtz_f16_f32 %0, %1, %2" : "=v"(r) : "v"(a), "v"(b));
  return r;
}

// key permutation for K-staging: bit shuffle [c1 c0 g1 g0 r1 r0] -> [c1 g1 g0 c0 r1 r0]
// so that QK D-rows land on true keys kk*32+g*8+(cb&1)*4+r.   (R6-validated)
#define PIDX(r) (((r) & 32) | (((r) & 12) << 1) | ((((r) >> 4) & 1) << 2) | ((r) & 3))

// ---------------- f32 -> f16 convert ----------------
__global__ void cvt_f32_f16_k(const float* __restrict__ src, f16* __restrict__ dst, int n4) {
  int i = blockIdx.x * blockDim.x + threadIdx.x;
  if (i >= n4) return;
  float4 v = ((const float4*)src)[i];
  f16x4 h;
  h[0] = (f16)v.x; h[1] = (f16)v.y; h[2] = (f16)v.z; h[3] = (f16)v.w;
  ((f16x4*)dst)[i] = h;
}

// ---------------- fused QKV projection GEMM ----------------
__global__ __launch_bounds__(256) void proj_gemm_k(
    const f16* __restrict__ A, const f16* __restrict__ W,
    const float* __restrict__ bq, const float* __restrict__ bk, const float* __restrict__ bv,
    f16* __restrict__ Out) {
  __shared__ __align__(16) f16 As[128 * 64];
  __shared__ __align__(16) f16 Bs[128 * 64];
  const int tid = threadIdx.x;
  const int l   = tid & 63;
  const int w   = tid >> 6;
  const int lr  = l & 15;
  const int lk  = (l >> 4) * 8;
  const int col0 = blockIdx.x * 128;
  const int row0 = blockIdx.y * 128;
  const int wr = (w >> 1) * 64;
  const int wc = (w & 1) * 64;

  f32x4 acc[4][4] = {};

  for (int kt = 0; kt < 16; ++kt) {
    const int k0 = kt * 64;
#pragma unroll
    for (int i = 0; i < 4; ++i) {
      const int c   = tid + i * 256;
      const int row = c >> 3;
      const int cb  = (c ^ row) & 7;
      g2lds16(A + (size_t)(row0 + row) * 1024 + k0 + cb * 8,
              As + (w * 64 + i * 256) * 8);
      g2lds16(W + (size_t)(col0 + row) * 1024 + k0 + cb * 8,
              Bs + (w * 64 + i * 256) * 8);
    }
    asm volatile("s_waitcnt vmcnt(0)" ::: "memory");
    __syncthreads();

#pragma unroll
    for (int kk = 0; kk < 64; kk += 32) {
      const int x = (kk + lk) >> 3;
      f16x8 af[4], bf[4];
#pragma unroll
      for (int m = 0; m < 4; ++m) {
        const int row = wr + m * 16 + lr;
        af[m] = *(const f16x8*)(As + (row * 8 + ((x ^ row) & 7)) * 8);
      }
#pragma unroll
      for (int n = 0; n < 4; ++n) {
        const int row = wc + n * 16 + lr;
        bf[n] = *(const f16x8*)(Bs + (row * 8 + ((x ^ row) & 7)) * 8);
      }
#pragma unroll
      for (int m = 0; m < 4; ++m)
#pragma unroll
        for (int n = 0; n < 4; ++n)
          acc[m][n] = __builtin_amdgcn_mfma_f32_16x16x32_f16(af[m], bf[n], acc[m][n], 0, 0, 0);
    }
    __syncthreads();
  }

  const int proj = col0 >> 10;
  const float* bias = (proj == 0) ? bq : ((proj == 1) ? bk : bv);
  f16* outp = Out + (size_t)proj * ((size_t)M_ * HID_);
#pragma unroll
  for (int n = 0; n < 4; ++n) {
    const int col = col0 + wc + n * 16 + lr;
    const int cp  = col & 1023;
    const float bb = bias[cp];
#pragma unroll
    for (int m = 0; m < 4; ++m) {
      const int rbase = row0 + wr + m * 16 + (l >> 4) * 4;
#pragma unroll
      for (int r = 0; r < 4; ++r)
        outp[(size_t)(rbase + r) * 1024 + cp] = (f16)(acc[m][n][r] + bb);
    }
  }
}

// ---------------- keff + V-transpose prep ----------------
// keff_s = C * (k/8 + softsign(softsign(k)/8) + v), C = 0.125*log2(e):
// QK MFMA output is then directly the exp2 argument (no per-score fmaf).
__global__ __launch_bounds__(256) void prep_kv_k(
    const f16* __restrict__ Kp, const f16* __restrict__ Vp,
    f16* __restrict__ Keff, f16* __restrict__ Vt) {
  const int bh = blockIdx.x;  // 64
  const int st = blockIdx.y;  // 32
  const int b = bh >> 4, h = bh & 15;
  const int tid = threadIdx.x;
  const float Cs = 0.180336880111120426f;  // 0.125 * log2(e)
#pragma unroll
  for (int i = 0; i < 2; ++i) {
    const int c  = tid + i * 256;
    const int sl = c >> 3, cb = c & 7;
    const int s  = st * 64 + sl;
    const size_t src = (size_t)(b * S_ + s) * 1024 + h * 64 + cb * 8;
    const f16x8 kv = *(const f16x8*)(Kp + src);
    const f16x8 vv = *(const f16x8*)(Vp + src);
    f16x8 ke;
#pragma unroll
    for (int j = 0; j < 8; ++j) {
      const float kf = (float)kv[j], vf = (float)vv[j];
      const float s1 = kf / (1.f + fabsf(kf));
      const float t  = s1 * 0.125f;
      const float s2 = t / (1.f + fabsf(t));
      ke[j] = (f16)((kf * 0.125f + s2 + vf) * Cs);
    }
    *(f16x8*)(Keff + ((size_t)bh * S_ + s) * 64 + cb * 8) = ke;
#pragma unroll
    for (int j = 0; j < 8; ++j)
      Vt[((size_t)bh * 64 + cb * 8 + j) * S_ + s] = vv[j];
  }
}

// ---------------- flash attention: 64 q-rows/wave, P in registers ----------------
// block = (bh, qtile of 128 rows), 2 waves x 64 q-rows (qb=0..3); K/V tiles 64, dbuf.
// Validated mappings (R6/R7): swapped QK + PIDX-staged K, in-lane pk16 pack.
// Softmax-lite: pe = exp2(dot_scaled) (scale folded into keff; no shift — it
// cancels in the division). Row-sum: R7-validated f32 lacc + epilogue shfl.
__global__ __launch_bounds__(128, 2) void attn_k(
    const f16* __restrict__ Q,     // [8192][1024]
    const f16* __restrict__ Keff,  // [64][2048][64]  (pre-scaled by C)
    const f16* __restrict__ Vt,    // [64][64][2048]
    const int* __restrict__ mask,  // [4][2048]
    float* __restrict__ Out) {     // [8192][1024] f32
  __shared__ __align__(16) f16 Kl[2][64 * 64];
  __shared__ __align__(16) f16 Vl[2][64 * 64];
  const int bh = blockIdx.x, qt = blockIdx.y;
  const int b = bh >> 4, h = bh & 15;
  const int tid = threadIdx.x;
  const int l = tid & 63, w = tid >> 6;   // w in {0,1}
  const int lr = l & 15, g = l >> 4;

  // Q fragments (B-operand of mfma(kf,qf)): lane (g,lr) holds
  // Q[qrow(lr)][kk*32 + g*8 .. +7]; zeroed if q-row masked.
  f16x8 qf[4][2];
#pragma unroll
  for (int qb = 0; qb < 4; ++qb) {
    const int qrow = qt * 128 + w * 64 + qb * 16 + lr;
    const f16* qs = Q + (size_t)(b * S_ + qrow) * 1024 + h * 64 + g * 8;
    qf[qb][0] = *(const f16x8*)(qs);
    qf[qb][1] = *(const f16x8*)(qs + 32);
    if (mask[b * S_ + qrow] == 0) {
      qf[qb][0] = (f16x8)(f16)0;
      qf[qb][1] = (f16x8)(f16)0;
    }
  }

  f32x4 ctx[4][4] = {};   // ctx[qb][db][r] = O[q=lr][d=db*16+g*4+r]
  float lacc[4] = {0.f, 0.f, 0.f, 0.f};

  // stage tile kt (128 threads): K rows PIDX-permuted, V true-key order; XOR swizzle.
#define STAGE(bf, kt2)                                                         \
  {                                                                            \
    _Pragma("unroll") for (int i = 0; i < 4; ++i) {                            \
      const int n = tid + i * 128;                                             \
      const int row = n >> 3, cl = n & 7;                                      \
      const int c = cl ^ (row & 7);                                            \
      g2lds16(Keff + ((size_t)bh * S_ + (kt2) * 64 + PIDX(row)) * 64 + c * 8,  \
              &Kl[bf][(w * 64 + i * 128) * 8]);                                \
      g2lds16(Vt + ((size_t)bh * 64 + row) * 2048 + (kt2) * 64 + c * 8,        \
              &Vl[bf][(w * 64 + i * 128) * 8]);                                \
    }                                                                          \
  }

  STAGE(0, 0);
  asm volatile("s_waitcnt vmcnt(0)" ::: "memory");
  __syncthreads();

  for (int kt = 0; kt < 32; ++kt) {
    const int cur = kt & 1;
    if (kt < 31) STAGE(cur ^ 1, kt + 1);

    // ---- QK + softmax-lite, processed in cb-pair slices to cap registers ----
    f16x8 pf[4][2];   // pf[qb][cbp]: P[q=lr][true keys cbp*32 + g*8 .. +7]
#pragma unroll
    for (int cbp = 0; cbp < 2; ++cbp) {
      f32x4 sv[4][2] = {};
      __builtin_amdgcn_s_setprio(1);
#pragma unroll
      for (int kk = 0; kk < 2; ++kk)
#pragma unroll
        for (int cc = 0; cc < 2; ++cc) {
          const int row = (cbp * 2 + cc) * 16 + lr;
          const f16x8 kf = *(const f16x8*)(&Kl[cur][(row * 8 + ((kk * 4 + g) ^ (row & 7))) * 8]);
#pragma unroll
          for (int qb = 0; qb < 4; ++qb)
            sv[qb][cc] = __builtin_amdgcn_mfma_f32_16x16x32_f16(kf, qf[qb][kk], sv[qb][cc], 0, 0, 0);
        }
      __builtin_amdgcn_s_setprio(0);
      // pe = exp2(dot_scaled); in-lane partial row-sum; pack to PV B-fragment
#pragma unroll
      for (int qb = 0; qb < 4; ++qb) {
        float pv[2][4];
        float s = 0.f;
#pragma unroll
        for (int cc = 0; cc < 2; ++cc)
#pragma unroll
          for (int r = 0; r < 4; ++r) {
            const float pe = exp2f(sv[qb][cc][r]);
            pv[cc][r] = pe;
            s += pe;
          }
        lacc[qb] += s;
        u32x4 pw = {pk16(pv[0][0], pv[0][1]), pk16(pv[0][2], pv[0][3]),
                    pk16(pv[1][0], pv[1][1]), pk16(pv[1][2], pv[1][3])};
        pf[qb][cbp] = __builtin_bit_cast(f16x8, pw);
      }
    }

    // ---- PV: mfma(vf, pf) ----
    __builtin_amdgcn_s_setprio(1);
#pragma unroll
    for (int kk = 0; kk < 2; ++kk)
#pragma unroll
      for (int db = 0; db < 4; ++db) {
        const int row = db * 16 + lr;
        const f16x8 vf = *(const f16x8*)(&Vl[cur][(row * 8 + ((kk * 4 + g) ^ (row & 7))) * 8]);
#pragma unroll
        for (int qb = 0; qb < 4; ++qb)
          ctx[qb][db] = __builtin_amdgcn_mfma_f32_16x16x32_f16(vf, pf[qb][kk], ctx[qb][db], 0, 0, 0);
      }
    __builtin_amdgcn_s_setprio(0);

    asm volatile("s_waitcnt vmcnt(0)" ::: "memory");
    __syncthreads();
  }

  // ---- finalize: sum lacc over the 4 g-groups (shfl), divide, store f32x4 ----
#pragma unroll
  for (int qb = 0; qb < 4; ++qb) {
    float ls = lacc[qb];
    ls += __shfl_xor(ls, 16);
    ls += __shfl_xor(ls, 32);
    const float linv = 1.0f / ls;
    const int qrow = qt * 128 + w * 64 + qb * 16 + lr;
    float* op = Out + (size_t)(b * S_ + qrow) * 1024 + h * 64 + g * 4;
#pragma unroll
    for (int db = 0; db < 4; ++db) {
      f32x4 o = ctx[qb][db] * linv;
      *(f32x4*)(op + db * 16) = o;
    }
  }
}

extern "C" void kernel_launch(void* const* d_in, const int* in_sizes, int n_in,
                              void* d_out, int out_size, void* d_ws, size_t ws_size,
                              hipStream_t stream) {
  const float* hs = (const float*)d_in[0];
  const float* Wq = (const float*)d_in[1];
  const float* bq = (const float*)d_in[2];
  const float* Wk = (const float*)d_in[3];
  const float* bk = (const float*)d_in[4];
  const float* Wv = (const float*)d_in[5];
  const float* bv = (const float*)d_in[6];
  const int* mask = (const int*)d_in[7];
  float* out = (float*)d_out;

  f16* hsF  = (f16*)d_ws;                       // 8192*1024
  f16* wF   = hsF + (size_t)M_ * HID_;          // 3*1024*1024
  f16* qF   = wF + 3ull * HID_ * HID_;          // 8192*1024
  f16* kF   = qF + (size_t)M_ * HID_;           // 8192*1024
  f16* vF   = kF + (size_t)M_ * HID_;           // 8192*1024
  f16* keff = vF + (size_t)M_ * HID_;           // 64*2048*64
  f16* vt   = keff + (size_t)M_ * HID_;         // 64*64*2048

  cvt_f32_f16_k<<<dim3((M_ * HID_) / 1024), 256, 0, stream>>>(hs, hsF, (M_ * HID_) / 4);
  cvt_f32_f16_k<<<dim3((HID_ * HID_) / 1024), 256, 0, stream>>>(Wq, wF, (HID_ * HID_) / 4);
  cvt_f32_f16_k<<<dim3((HID_ * HID_) / 1024), 256, 0, stream>>>(Wk, wF + (size_t)HID_ * HID_, (HID_ * HID_) / 4);
  cvt_f32_f16_k<<<dim3((HID_ * HID_) / 1024), 256, 0, stream>>>(Wv, wF + 2ull * (size_t)HID_ * HID_, (HID_ * HID_) / 4);

  proj_gemm_k<<<dim3(24, 64), 256, 0, stream>>>(hsF, wF, bq, bk, bv, qF);
  prep_kv_k<<<dim3(64, 32), 256, 0, stream>>>(kF, vF, keff, vt);
  attn_k<<<dim3(64, 16), 128, 0, stream>>>(qF, keff, vt, mask, out);
}